// Round 13
// baseline (1620.540 us; speedup 1.0000x reference)
//
#include <hip/hip_runtime.h>

#define N_NODES 20000
#define N_EDGES 320000
#define DIM 128
#define NLAYER 3
#define NBLK 1024
#define NSCAN 79  // ceil(20000/256)
#define LDS_STRIDE 136

typedef __attribute__((ext_vector_type(8))) short short8;
typedef __attribute__((ext_vector_type(4))) float f32x4;
typedef __attribute__((ext_vector_type(2))) float f32x2;

__device__ inline ushort f2bf(float f) {
  uint u = __float_as_uint(f);
  uint r = (u + 0x7fffu + ((u >> 16) & 1u)) >> 16;
  return (ushort)r;
}
__device__ inline float bf2f(ushort u) { return __uint_as_float(((uint)u) << 16); }
__device__ inline uint f2fp8(float f) {
  return __builtin_amdgcn_cvt_pk_fp8_f32(f, 0.f, 0, false) & 0xffu;
}
__device__ inline void fp8x4_to_f32(uint w, float* o) {
  f32x2 lo = __builtin_amdgcn_cvt_pk_f32_fp8(w, false);
  f32x2 hi = __builtin_amdgcn_cvt_pk_f32_fp8(w, true);
  o[0] = lo[0]; o[1] = lo[1]; o[2] = hi[0]; o[3] = hi[1];
}

// device-scope generation barrier: slot idx, all NBLK blocks co-resident.
__device__ inline void gbar(int* cnt, int idx) {
  __syncthreads();  // drains this block's memory ops (compiler emits waitcnt)
  if (threadIdx.x == 0) {
    // ACQ_REL agent-scope RMW: release (L2 writeback) of this block's stores
    __hip_atomic_fetch_add(&cnt[idx], 1, __ATOMIC_ACQ_REL, __HIP_MEMORY_SCOPE_AGENT);
    int v = 0;
    while (v < NBLK) {
      v = __hip_atomic_load(&cnt[idx], __ATOMIC_RELAXED, __HIP_MEMORY_SCOPE_AGENT);
      if (v < NBLK) __builtin_amdgcn_s_sleep(2);
    }
  }
  __syncthreads();
  __threadfence();  // acquire: invalidate L1/L2 so we observe other XCDs' writes
}

// ---------------- gemm tile (r11 body, runtime mode) ----------------
// mode: 0 = bf16 row-major; 1 = f32 row-major; 2 = fp8 kv k-slot; 3 = v-slot.
__device__ void gemm_tile(const void* Xp, int in_f32, const ushort* Wt,
                          const float* bias, void* O, int mode, int bx,
                          char* smem) {
  ushort* As = (ushort*)smem;
  int t = threadIdx.x;
  int wid = t >> 6, lane = t & 63;
  int row0 = bx * 128;
  int wr = wid >> 1, wc = wid & 1;
  int lr = lane & 15;
  int kc8 = (lane >> 4) * 8;

  if (in_f32) {
    const float* Xf = (const float*)Xp;
    int rowi = t >> 5;
    int col4 = (t & 31) * 4;
    #pragma unroll
    for (int pass = 0; pass < 16; ++pass) {
      int row = pass * 8 + rowi;
      int gr = min(row0 + row, N_NODES - 1);
      float4 f = *(const float4*)(Xf + (size_t)gr * DIM + col4);
      ushort4 u;
      u.x = f2bf(f.x); u.y = f2bf(f.y); u.z = f2bf(f.z); u.w = f2bf(f.w);
      *(ushort4*)(As + row * LDS_STRIDE + col4) = u;
    }
  } else {
    const ushort* X = (const ushort*)Xp;
    int rowi = t >> 4;
    int col = (t & 15) * 8;
    #pragma unroll
    for (int pass = 0; pass < 8; ++pass) {
      int row = pass * 16 + rowi;
      int gr = min(row0 + row, N_NODES - 1);
      short8 val = *(const short8*)(X + (size_t)gr * DIM + col);
      *(short8*)(As + row * LDS_STRIDE + col) = val;
    }
  }
  __syncthreads();

  f32x4 acc[4][4];
  #pragma unroll
  for (int i = 0; i < 4; ++i)
    #pragma unroll
    for (int j = 0; j < 4; ++j) acc[i][j] = (f32x4){0.f, 0.f, 0.f, 0.f};

  #pragma unroll
  for (int ks = 0; ks < 4; ++ks) {
    short8 b[4];
    #pragma unroll
    for (int cf = 0; cf < 4; ++cf) {
      int c = wc * 64 + cf * 16 + lr;
      b[cf] = *(const short8*)(Wt + (size_t)c * DIM + ks * 32 + kc8);
    }
    #pragma unroll
    for (int rf = 0; rf < 4; ++rf) {
      int r = wr * 64 + rf * 16 + lr;
      short8 a = *(const short8*)(As + r * LDS_STRIDE + ks * 32 + kc8);
      #pragma unroll
      for (int cf = 0; cf < 4; ++cf)
        acc[rf][cf] = __builtin_amdgcn_mfma_f32_16x16x32_bf16(a, b[cf], acc[rf][cf], 0, 0, 0);
    }
  }
  __syncthreads();  // As reuse safety for next grid-stride tile

  // C/D layout: col = lane&15, row = (lane>>4)*4 + reg  [m89-verified]
  #pragma unroll
  for (int cf = 0; cf < 4; ++cf) {
    int c = wc * 64 + cf * 16 + lr;
    float bv = bias[c];
    #pragma unroll
    for (int rf = 0; rf < 4; ++rf) {
      #pragma unroll
      for (int reg = 0; reg < 4; ++reg) {
        int r = row0 + wr * 64 + rf * 16 + (lane >> 4) * 4 + reg;
        if (r < N_NODES) {
          float val = acc[rf][cf][reg] + bv;
          if (mode == 0)
            ((ushort*)O)[(size_t)r * DIM + c] = f2bf(val);
          else if (mode == 1)
            ((float*)O)[(size_t)r * DIM + c] = val;
          else if (mode == 2)
            ((unsigned char*)O)[(size_t)r * 256 + c] = (unsigned char)f2fp8(val);
          else
            ((unsigned char*)O)[(size_t)r * 256 + 128 + c] = (unsigned char)f2fp8(val);
        }
      }
    }
  }
}

// ---------------- attention node-group (r11 body) ----------------
__device__ void attn_group(int g, const ushort* q, const unsigned char* kv,
                           const ushort* xr, const void* xres, int res_f32,
                           const int* rowptr, const int* csr_src,
                           const float* wbeta, const float* lng,
                           const float* lnb, ushort* xnextb, char* smem) {
  float (*red)[8][8][20] = (float (*)[8][8][20])smem;
  int w = threadIdx.x >> 6;
  int lane = threadIdx.x & 63;
  int n = g * 4 + w;
  int h = lane & 7, e = lane >> 3;

  const ushort* qrow = q + (size_t)n * DIM + h * 16;
  short8 q0 = *(const short8*)qrow;
  short8 q1 = *(const short8*)(qrow + 8);
  float qf[16];
  #pragma unroll
  for (int i = 0; i < 8; ++i) {
    qf[i] = bf2f((ushort)q0[i]) * 0.25f;
    qf[8 + i] = bf2f((ushort)q1[i]) * 0.25f;
  }

  int s0 = rowptr[n];
  int deg = rowptr[n + 1] - s0;
  float acc[16];
  #pragma unroll
  for (int i = 0; i < 16; ++i) acc[i] = 0.f;
  float dsum = 0.f;

  int src_n = (deg > 0) ? csr_src[s0 + min(e, deg - 1)] : 0;
  for (int base = 0; base < deg; base += 8) {
    int idx = base + e;
    bool valid = idx < deg;
    int src = src_n;
    if (base + 8 < deg)
      src_n = csr_src[s0 + min(base + 8 + e, deg - 1)];
    const unsigned char* rec = kv + (size_t)src * 256 + h * 16;
    uint4 ku = *(const uint4*)rec;
    uint4 vu = *(const uint4*)(rec + 128);
    float kf[16], vf[16];
    fp8x4_to_f32(ku.x, kf + 0);
    fp8x4_to_f32(ku.y, kf + 4);
    fp8x4_to_f32(ku.z, kf + 8);
    fp8x4_to_f32(ku.w, kf + 12);
    fp8x4_to_f32(vu.x, vf + 0);
    fp8x4_to_f32(vu.y, vf + 4);
    fp8x4_to_f32(vu.z, vf + 8);
    fp8x4_to_f32(vu.w, vf + 12);
    float p = 0.f;
    #pragma unroll
    for (int i = 0; i < 16; ++i) p = fmaf(qf[i], kf[i], p);
    float ea = __expf(p);
    ea = valid ? ea : 0.f;
    dsum += ea;
    #pragma unroll
    for (int i = 0; i < 16; ++i) acc[i] = fmaf(ea, vf[i], acc[i]);
  }

  {
    float* my = &red[w][e][h][0];
    *(float4*)(my + 0) = make_float4(acc[0], acc[1], acc[2], acc[3]);
    *(float4*)(my + 4) = make_float4(acc[4], acc[5], acc[6], acc[7]);
    *(float4*)(my + 8) = make_float4(acc[8], acc[9], acc[10], acc[11]);
    *(float4*)(my + 12) = make_float4(acc[12], acc[13], acc[14], acc[15]);
    my[16] = dsum;
  }
  asm volatile("s_waitcnt lgkmcnt(0)" ::: "memory");

  int c0 = lane * 2;
  int hh = lane >> 3, cc = (lane & 7) * 2;
  float o0 = 0.f, o1 = 0.f, den = 0.f;
  #pragma unroll
  for (int ee = 0; ee < 8; ++ee) {
    float2 tv = *(float2*)&red[w][ee][hh][cc];
    o0 += tv.x;
    o1 += tv.y;
    den += red[w][ee][hh][16];
  }
  float inv = 1.f / (den + 1e-16f);
  o0 *= inv;
  o1 *= inv;

  ushort2 xru = *(const ushort2*)(xr + (size_t)n * DIM + c0);
  float xr0 = bf2f(xru.x), xr1 = bf2f(xru.y);
  float wa0 = wbeta[c0] + wbeta[2 * DIM + c0];
  float wa1 = wbeta[c0 + 1] + wbeta[2 * DIM + c0 + 1];
  float wb0 = wbeta[DIM + c0] - wbeta[2 * DIM + c0];
  float wb1 = wbeta[DIM + c0 + 1] - wbeta[2 * DIM + c0 + 1];
  float bs = o0 * wa0 + o1 * wa1 + xr0 * wb0 + xr1 * wb1;
  #pragma unroll
  for (int off = 1; off < 64; off <<= 1) bs += __shfl_xor(bs, off);
  float beta = 1.f / (1.f + __expf(-bs));
  float y0 = fmaxf(beta * xr0 + (1.f - beta) * o0, 0.f);
  float y1 = fmaxf(beta * xr1 + (1.f - beta) * o1, 0.f);
  float rv0, rv1;
  if (res_f32) {
    float2 rv = *(const float2*)((const float*)xres + (size_t)n * DIM + c0);
    rv0 = rv.x; rv1 = rv.y;
  } else {
    ushort2 ru = *(const ushort2*)((const ushort*)xres + (size_t)n * DIM + c0);
    rv0 = bf2f(ru.x); rv1 = bf2f(ru.y);
  }
  y0 += rv0;
  y1 += rv1;
  float s = y0 + y1;
  #pragma unroll
  for (int off = 1; off < 64; off <<= 1) s += __shfl_xor(s, off);
  float mu = s * (1.f / 128.f);
  float d0 = y0 - mu, d1 = y1 - mu;
  float vs = d0 * d0 + d1 * d1;
  #pragma unroll
  for (int off = 1; off < 64; off <<= 1) vs += __shfl_xor(vs, off);
  float rstd = rsqrtf(vs * (1.f / 128.f) + 1e-5f);
  float2 g2 = *(const float2*)(lng + c0);
  float2 b2 = *(const float2*)(lnb + c0);
  float out0 = d0 * rstd * g2.x + b2.x;
  float out1 = d1 * rstd * g2.y + b2.y;
  ushort2 ob;
  ob.x = f2bf(out0);
  ob.y = f2bf(out1);
  *(ushort2*)(xnextb + (size_t)n * DIM + c0) = ob;
}

// ---------------- the mega kernel ----------------
__global__ __launch_bounds__(256, 4) void mega_kernel(
    const float* __restrict__ x_in, const int* __restrict__ ei,
    const float* __restrict__ Wq, const float* __restrict__ bq,
    const float* __restrict__ Wk, const float* __restrict__ bk,
    const float* __restrict__ Wv, const float* __restrict__ bv,
    const float* __restrict__ Wsk, const float* __restrict__ bsk,
    const float* __restrict__ Wb, const float* __restrict__ lng,
    const float* __restrict__ lnb, const float* __restrict__ Wout,
    const float* __restrict__ bout, float* __restrict__ out,
    ushort* __restrict__ xbb, ushort* __restrict__ qb,
    unsigned char* __restrict__ kvb, ushort* __restrict__ xrb,
    ushort* __restrict__ wt, int* __restrict__ rowptr, int* __restrict__ degc,
    int* __restrict__ bsum, int* __restrict__ csr_src, int* __restrict__ barcnt) {
  __shared__ __align__(16) char smem[34816];
  __shared__ int sc_ws[6];
  int b = blockIdx.x, t = threadIdx.x;

  // ---- P0: weight cast (blocks 0..207) | zero degc/bsum (blocks 208+) ----
  if (b < 208) {
    float (*tile)[33] = (float (*)[33])smem;
    int z = b >> 4, r = b & 15;
    int k0 = (r >> 2) * 32, n0 = (r & 3) * 32;
    const float* src;
    if (z < 12) {
      int l = z >> 2, j = z & 3;
      src = (j == 0 ? Wq : j == 1 ? Wk : j == 2 ? Wv : Wsk) + (size_t)l * DIM * DIM;
    } else {
      src = Wout;
    }
    int tx = t & 31, ty = t >> 5;
    #pragma unroll
    for (int i = 0; i < 32; i += 8)
      tile[ty + i][tx] = src[(size_t)(k0 + ty + i) * DIM + n0 + tx];
    __syncthreads();
    ushort* dst = wt + (size_t)z * DIM * DIM;
    #pragma unroll
    for (int i = 0; i < 32; i += 8)
      dst[(size_t)(n0 + ty + i) * DIM + k0 + tx] = f2bf(tile[tx][ty + i]);
  } else {
    int i = (b - 208) * 256 + t;
    if (i < N_NODES) degc[i] = 0;
    else if (i < N_NODES + 128) bsum[i - N_NODES] = 0;
  }
  gbar(barcnt, 0);

  // ---- P1: count degrees ----
  for (int e = b * 256 + t; e < N_EDGES; e += NBLK * 256)
    atomicAdd(&degc[ei[N_EDGES + e]], 1);
  gbar(barcnt, 1);

  // ---- P2: scan (blocks 0..78; lookback over published block sums) ----
  if (b < NSCAN) {
    int lane = t & 63, w = t >> 6;
    int i = b * 256 + t;
    int val = (i < N_NODES) ? degc[i] : 0;
    if (i < N_NODES) degc[i] = 0;  // becomes the scatter cursor
    int s = val;
    #pragma unroll
    for (int off = 1; off < 64; off <<= 1) {
      int u = __shfl_up(s, off);
      if (lane >= off) s += u;
    }
    if (lane == 63) sc_ws[w] = s;
    __syncthreads();
    if (t == 0) {
      int a0 = sc_ws[0], a1 = sc_ws[1], a2 = sc_ws[2], a3 = sc_ws[3];
      sc_ws[0] = 0; sc_ws[1] = a0; sc_ws[2] = a0 + a1; sc_ws[3] = a0 + a1 + a2;
      int btot = a0 + a1 + a2 + a3;
      sc_ws[4] = btot;
      __hip_atomic_store(&bsum[b], btot + 1, __ATOMIC_RELEASE,
                         __HIP_MEMORY_SCOPE_AGENT);
    }
    __syncthreads();
    int excl = sc_ws[w] + s - val;
    if (w == 0) {
      int p = 0;
      for (int j = lane; j < b; j += 64) {
        int v;
        do {
          v = __hip_atomic_load(&bsum[j], __ATOMIC_ACQUIRE, __HIP_MEMORY_SCOPE_AGENT);
        } while (v == 0);
        p += v - 1;
      }
      #pragma unroll
      for (int off = 1; off < 64; off <<= 1) p += __shfl_xor(p, off);
      if (t == 0) sc_ws[5] = p;
    }
    __syncthreads();
    int off0 = sc_ws[5];
    if (i < N_NODES) rowptr[i] = off0 + excl;
    if (b == NSCAN - 1 && t == 255) rowptr[N_NODES] = off0 + sc_ws[4];
  }
  gbar(barcnt, 2);

  // ---- P3: scatter edges into CSR ----
  for (int e = b * 256 + t; e < N_EDGES; e += NBLK * 256) {
    int d = ei[N_EDGES + e];
    int srcn = ei[e];
    int pos = atomicAdd(&degc[d], 1);
    csr_src[rowptr[d] + pos] = srcn;
  }
  gbar(barcnt, 3);

  // ---- layers ----
  int bi = 4;
  for (int l = 0; l < NLAYER; ++l) {
    const void* xin_l = (l == 0) ? (const void*)x_in : (const void*)xbb;
    int in_f32 = (l == 0) ? 1 : 0;
    for (int tile = b; tile < 157 * 4; tile += NBLK) {
      int bx = tile >> 2, mat = tile & 3;
      const float* bias =
          (mat == 0 ? bq : mat == 1 ? bk : mat == 2 ? bv : bsk) + (size_t)l * DIM;
      void* O = (mat == 0) ? (void*)qb : (mat == 3) ? (void*)xrb : (void*)kvb;
      int mode = (mat == 0) ? 0 : (mat == 1) ? 2 : (mat == 2) ? 3 : 0;
      gemm_tile(xin_l, in_f32, wt + (size_t)(l * 4 + mat) * DIM * DIM, bias, O,
                mode, bx, smem);
    }
    gbar(barcnt, bi++);
    const void* xres = (l == 0) ? (const void*)x_in : (const void*)xbb;
    for (int g = b; g < N_NODES / 4; g += NBLK)
      attn_group(g, qb, kvb, xrb, xres, (l == 0) ? 1 : 0, rowptr, csr_src,
                 Wb + (size_t)l * 3 * DIM, lng + (size_t)l * DIM,
                 lnb + (size_t)l * DIM, xbb, smem);
    gbar(barcnt, bi++);
  }

  // ---- final projection: out = x @ Wout + bout (fp32) ----
  for (int tile = b; tile < 157; tile += NBLK)
    gemm_tile((const void*)xbb, 0, wt + (size_t)12 * DIM * DIM, bout, (void*)out,
              1, tile, smem);
}

// ---------------- launch ----------------

extern "C" void kernel_launch(void* const* d_in, const int* in_sizes, int n_in,
                              void* d_out, int out_size, void* d_ws, size_t ws_size,
                              hipStream_t stream) {
  const float* x_in = (const float*)d_in[0];
  const int* ei = (const int*)d_in[1];
  const float* Wq = (const float*)d_in[2];
  const float* bq = (const float*)d_in[3];
  const float* Wk = (const float*)d_in[4];
  const float* bk = (const float*)d_in[5];
  const float* Wv = (const float*)d_in[6];
  const float* bv = (const float*)d_in[7];
  const float* Wsk = (const float*)d_in[8];
  const float* bsk = (const float*)d_in[9];
  const float* Wb = (const float*)d_in[10];
  const float* lng = (const float*)d_in[11];
  const float* lnb = (const float*)d_in[12];
  const float* Wout = (const float*)d_in[13];
  const float* bout = (const float*)d_in[14];
  float* out = (float*)d_out;

  char* p = (char*)d_ws;
  auto alloc = [&](size_t bytes) {
    char* r = p;
    p += (bytes + 255) & ~(size_t)255;
    return r;
  };
  const size_t NB2 = (size_t)N_NODES * DIM * 2;
  ushort* xbb = (ushort*)alloc(NB2);
  ushort* qb = (ushort*)alloc(NB2);
  unsigned char* kvb = (unsigned char*)alloc((size_t)N_NODES * 256);
  ushort* xrb = (ushort*)alloc(NB2);
  ushort* wt = (ushort*)alloc((size_t)13 * DIM * DIM * 2);
  int* rowptr = (int*)alloc((N_NODES + 1) * 4);
  int* degc = (int*)alloc(N_NODES * 4);
  int* bsum = (int*)alloc(128 * 4);
  int* csr_src = (int*)alloc(N_EDGES * 4);
  int* barcnt = (int*)alloc(16 * 4);

  hipMemsetAsync(barcnt, 0, 16 * 4, stream);
  mega_kernel<<<NBLK, 256, 0, stream>>>(
      x_in, ei, Wq, bq, Wk, bk, Wv, bv, Wsk, bsk, Wb, lng, lnb, Wout, bout, out,
      xbb, qb, kvb, xrb, wt, rowptr, degc, bsum, csr_src, barcnt);
}

// Round 14
// 190.089 us; speedup vs baseline: 8.5252x; 8.5252x over previous
//
#include <hip/hip_runtime.h>

#define N_NODES 20000
#define N_EDGES 320000
#define DIM 128
#define NLAYER 3
#define SCAN_BLK 1024
#define N_SCAN_BLKS ((N_NODES + SCAN_BLK - 1) / SCAN_BLK)  // 20
#define LDS_STRIDE 136

#define PREP_CASTW_BLKS 208
#define PREP_ZERO_BLKS 79
#define PREP_TOTAL (PREP_CASTW_BLKS + PREP_ZERO_BLKS)

typedef __attribute__((ext_vector_type(8))) short short8;
typedef __attribute__((ext_vector_type(4))) float f32x4;
typedef __attribute__((ext_vector_type(2))) float f32x2;

__device__ inline ushort f2bf(float f) {
  uint u = __float_as_uint(f);
  uint r = (u + 0x7fffu + ((u >> 16) & 1u)) >> 16;
  return (ushort)r;
}
__device__ inline float bf2f(ushort u) { return __uint_as_float(((uint)u) << 16); }

__device__ inline uint f2fp8(float f) {
  return __builtin_amdgcn_cvt_pk_fp8_f32(f, 0.f, 0, false) & 0xffu;
}
__device__ inline void fp8x4_to_f32(uint w, float* o) {
  f32x2 lo = __builtin_amdgcn_cvt_pk_f32_fp8(w, false);
  f32x2 hi = __builtin_amdgcn_cvt_pk_f32_fp8(w, true);
  o[0] = lo[0]; o[1] = lo[1]; o[2] = hi[0]; o[3] = hi[1];
}

// ---------------- fused prep: cast_w | zero degc + scan state ----------------
__global__ __launch_bounds__(256) void prep_kernel(
    const float* __restrict__ Wq, const float* __restrict__ Wk,
    const float* __restrict__ Wv, const float* __restrict__ Ws,
    const float* __restrict__ Wo, ushort* __restrict__ wt,
    int* __restrict__ degc, int* __restrict__ bsum) {
  int b = blockIdx.x;
  int t = threadIdx.x;
  if (b < PREP_CASTW_BLKS) {
    int z = b >> 4;
    int r = b & 15;
    int k0 = (r >> 2) * 32, n0 = (r & 3) * 32;
    const float* src;
    if (z < 12) {
      int l = z >> 2, j = z & 3;
      src = (j == 0 ? Wq : j == 1 ? Wk : j == 2 ? Wv : Ws) + (size_t)l * DIM * DIM;
    } else {
      src = Wo;
    }
    __shared__ float tile[32][33];
    int tx = t & 31, ty = t >> 5;
    #pragma unroll
    for (int i = 0; i < 32; i += 8)
      tile[ty + i][tx] = src[(size_t)(k0 + ty + i) * DIM + n0 + tx];
    __syncthreads();
    ushort* dst = wt + (size_t)z * DIM * DIM;
    #pragma unroll
    for (int i = 0; i < 32; i += 8)
      dst[(size_t)(n0 + ty + i) * DIM + k0 + tx] = f2bf(tile[tx][ty + i]);
  } else {
    int i = (b - PREP_CASTW_BLKS) * 256 + t;
    if (i < N_NODES) degc[i] = 0;
    else if (i < N_NODES + N_SCAN_BLKS) bsum[i - N_NODES] = 0;
  }
}

// ---------------- CSR build ----------------

__global__ void count_deg_kernel(const int* __restrict__ ei, int* __restrict__ deg) {
  int e = blockIdx.x * 256 + threadIdx.x;
  if (e < N_EDGES) atomicAdd(&deg[ei[N_EDGES + e]], 1);
}

// single-dispatch exclusive scan via decoupled lookback (20 co-resident blocks).
// Also re-zeroes degc (scatter cursor). Deterministic: published values are
// timing-independent; +1 marker distinguishes "not yet published".
__global__ __launch_bounds__(SCAN_BLK) void scan_lookback_kernel(
    int* __restrict__ degc, int* __restrict__ rowptr, int* __restrict__ bsum) {
  __shared__ int wsum[16];
  __shared__ int prevs;
  int t = threadIdx.x, lane = t & 63, w = t >> 6, bid = blockIdx.x;
  int i = bid * SCAN_BLK + t;
  int val = (i < N_NODES) ? degc[i] : 0;
  if (i < N_NODES) degc[i] = 0;
  int s = val;
  #pragma unroll
  for (int off = 1; off < 64; off <<= 1) {
    int u = __shfl_up(s, off);
    if (lane >= off) s += u;
  }
  if (lane == 63) wsum[w] = s;
  __syncthreads();
  if (t < 16) {
    int wv = wsum[t];
    int ss = wv;
    #pragma unroll
    for (int off = 1; off < 16; off <<= 1) {
      int u = __shfl_up(ss, off);
      if (t >= off) ss += u;
    }
    wsum[t] = ss - wv;
  }
  __syncthreads();
  int excl = wsum[w] + s - val;
  if (t == SCAN_BLK - 1)
    __hip_atomic_store(&bsum[bid], excl + val + 1, __ATOMIC_RELEASE,
                       __HIP_MEMORY_SCOPE_AGENT);
  if (w == 0) {
    int p = 0;
    for (int j = lane; j < bid; j += 64) {
      int v;
      do {
        v = __hip_atomic_load(&bsum[j], __ATOMIC_ACQUIRE, __HIP_MEMORY_SCOPE_AGENT);
      } while (v == 0);
      p += v - 1;
    }
    #pragma unroll
    for (int off = 1; off < 64; off <<= 1) p += __shfl_xor(p, off);
    if (t == 0) prevs = p;
  }
  __syncthreads();
  int off0 = prevs;
  if (i < N_NODES) rowptr[i] = off0 + excl;
  if (bid == N_SCAN_BLKS - 1 && t == SCAN_BLK - 1) rowptr[N_NODES] = off0 + excl + val;
}

__global__ void scatter_kernel(const int* __restrict__ ei, const int* __restrict__ rowptr,
                               int* __restrict__ cursor, int* __restrict__ csr_src) {
  int e = blockIdx.x * 256 + threadIdx.x;
  if (e < N_EDGES) {
    int d = ei[N_EDGES + e];
    int s = ei[e];
    int pos = atomicAdd(&cursor[d], 1);
    csr_src[rowptr[d] + pos] = s;
  }
}

// ---------------- bf16 MFMA GEMM (256 thr, 4 waves, wave tile 64x64) ----------
// Output modes: 0 = bf16 row-major; 1 = f32 row-major; 2 = fp8 kv k-slot; 3 = v-slot.
template <int IN_F32>
__global__ __launch_bounds__(256) void gemm_mfma_kernel(
    const void* __restrict__ Xp, const ushort* __restrict__ WT,
    const float* __restrict__ B0, const float* __restrict__ B1,
    const float* __restrict__ B2, const float* __restrict__ B3,
    void* __restrict__ O0, void* __restrict__ O1, void* __restrict__ O2,
    void* __restrict__ O3, int m0, int m1, int m2, int m3) {
  __shared__ ushort As[128 * LDS_STRIDE];
  int mat = blockIdx.y;
  const ushort* Wt = WT + (size_t)mat * DIM * DIM;
  const float* bias;
  void* O;
  int mode;
  switch (mat) {
    case 0: bias = B0; O = O0; mode = m0; break;
    case 1: bias = B1; O = O1; mode = m1; break;
    case 2: bias = B2; O = O2; mode = m2; break;
    default: bias = B3; O = O3; mode = m3; break;
  }
  int t = threadIdx.x;
  int wid = t >> 6, lane = t & 63;
  int row0 = blockIdx.x * 128;
  int wr = wid >> 1, wc = wid & 1;
  int lr = lane & 15;
  int kc8 = (lane >> 4) * 8;

  if (IN_F32) {
    const float* Xf = (const float*)Xp;
    int rowi = t >> 5;
    int col4 = (t & 31) * 4;
    #pragma unroll
    for (int pass = 0; pass < 16; ++pass) {
      int row = pass * 8 + rowi;
      int gr = min(row0 + row, N_NODES - 1);
      float4 f = *(const float4*)(Xf + (size_t)gr * DIM + col4);
      ushort4 u;
      u.x = f2bf(f.x); u.y = f2bf(f.y); u.z = f2bf(f.z); u.w = f2bf(f.w);
      *(ushort4*)(As + row * LDS_STRIDE + col4) = u;
    }
  } else {
    const ushort* X = (const ushort*)Xp;
    int rowi = t >> 4;
    int col = (t & 15) * 8;
    #pragma unroll
    for (int pass = 0; pass < 8; ++pass) {
      int row = pass * 16 + rowi;
      int gr = min(row0 + row, N_NODES - 1);
      short8 val = *(const short8*)(X + (size_t)gr * DIM + col);
      *(short8*)(As + row * LDS_STRIDE + col) = val;
    }
  }
  __syncthreads();

  f32x4 acc[4][4];
  #pragma unroll
  for (int i = 0; i < 4; ++i)
    #pragma unroll
    for (int j = 0; j < 4; ++j) acc[i][j] = (f32x4){0.f, 0.f, 0.f, 0.f};

  #pragma unroll
  for (int ks = 0; ks < 4; ++ks) {
    short8 b[4];
    #pragma unroll
    for (int cf = 0; cf < 4; ++cf) {
      int c = wc * 64 + cf * 16 + lr;
      b[cf] = *(const short8*)(Wt + (size_t)c * DIM + ks * 32 + kc8);
    }
    #pragma unroll
    for (int rf = 0; rf < 4; ++rf) {
      int r = wr * 64 + rf * 16 + lr;
      short8 a = *(const short8*)(As + r * LDS_STRIDE + ks * 32 + kc8);
      #pragma unroll
      for (int cf = 0; cf < 4; ++cf)
        acc[rf][cf] = __builtin_amdgcn_mfma_f32_16x16x32_bf16(a, b[cf], acc[rf][cf], 0, 0, 0);
    }
  }

  // C/D layout: col = lane&15, row = (lane>>4)*4 + reg  [m89-verified]
  #pragma unroll
  for (int cf = 0; cf < 4; ++cf) {
    int c = wc * 64 + cf * 16 + lr;
    float bv = bias[c];
    #pragma unroll
    for (int rf = 0; rf < 4; ++rf) {
      #pragma unroll
      for (int reg = 0; reg < 4; ++reg) {
        int r = row0 + wr * 64 + rf * 16 + (lane >> 4) * 4 + reg;
        if (r < N_NODES) {
          float val = acc[rf][cf][reg] + bv;
          if (mode == 0)
            ((ushort*)O)[(size_t)r * DIM + c] = f2bf(val);
          else if (mode == 1)
            ((float*)O)[(size_t)r * DIM + c] = val;
          else if (mode == 2)
            ((unsigned char*)O)[(size_t)r * 256 + c] = (unsigned char)f2fp8(val);
          else
            ((unsigned char*)O)[(size_t)r * 256 + 128 + c] = (unsigned char)f2fp8(val);
        }
      }
    }
  }
}

// ---------------- fused attention + beta-skip + relu + residual + layernorm --------
// One wave per dst node (4/block), lane = (e=lane>>3, h=lane&7); single-group loop
// with csr prefetch; fp8 kv record [node][k:128B | v:128B]; LDS transpose reduce.
// RES_F32: layer 0 reads fp32 residual (x_in); layers 1,2 bf16 xbb (in-place).
template <int RES_F32>
__global__ __launch_bounds__(256) void attn_fused_kernel(
    const ushort* __restrict__ q, const unsigned char* __restrict__ kv,
    const ushort* __restrict__ xr, const void* __restrict__ xres,
    const int* __restrict__ rowptr, const int* __restrict__ csr_src,
    const float* __restrict__ wbeta, const float* __restrict__ lng,
    const float* __restrict__ lnb, ushort* __restrict__ xnextb) {
  __shared__ float red[4][8][8][20];
  int w = threadIdx.x >> 6;
  int lane = threadIdx.x & 63;
  int n = blockIdx.x * 4 + w;
  int h = lane & 7, e = lane >> 3;

  const ushort* qrow = q + (size_t)n * DIM + h * 16;
  short8 q0 = *(const short8*)qrow;
  short8 q1 = *(const short8*)(qrow + 8);
  float qf[16];
  #pragma unroll
  for (int i = 0; i < 8; ++i) {
    qf[i] = bf2f((ushort)q0[i]) * 0.25f;
    qf[8 + i] = bf2f((ushort)q1[i]) * 0.25f;
  }

  int s0 = rowptr[n];
  int deg = rowptr[n + 1] - s0;
  float acc[16];
  #pragma unroll
  for (int i = 0; i < 16; ++i) acc[i] = 0.f;
  float dsum = 0.f;

  int src_n = (deg > 0) ? csr_src[s0 + min(e, deg - 1)] : 0;
  for (int base = 0; base < deg; base += 8) {
    int idx = base + e;
    bool valid = idx < deg;
    int src = src_n;
    if (base + 8 < deg)
      src_n = csr_src[s0 + min(base + 8 + e, deg - 1)];
    const unsigned char* rec = kv + (size_t)src * 256 + h * 16;
    uint4 ku = *(const uint4*)rec;
    uint4 vu = *(const uint4*)(rec + 128);
    float kf[16], vf[16];
    fp8x4_to_f32(ku.x, kf + 0);
    fp8x4_to_f32(ku.y, kf + 4);
    fp8x4_to_f32(ku.z, kf + 8);
    fp8x4_to_f32(ku.w, kf + 12);
    fp8x4_to_f32(vu.x, vf + 0);
    fp8x4_to_f32(vu.y, vf + 4);
    fp8x4_to_f32(vu.z, vf + 8);
    fp8x4_to_f32(vu.w, vf + 12);
    float p = 0.f;
    #pragma unroll
    for (int i = 0; i < 16; ++i) p = fmaf(qf[i], kf[i], p);
    float ea = __expf(p);
    ea = valid ? ea : 0.f;
    dsum += ea;
    #pragma unroll
    for (int i = 0; i < 16; ++i) acc[i] = fmaf(ea, vf[i], acc[i]);
  }

  // LDS transpose reduce over the 8 e-lanes (wave-private)
  {
    float* my = &red[w][e][h][0];
    *(float4*)(my + 0) = make_float4(acc[0], acc[1], acc[2], acc[3]);
    *(float4*)(my + 4) = make_float4(acc[4], acc[5], acc[6], acc[7]);
    *(float4*)(my + 8) = make_float4(acc[8], acc[9], acc[10], acc[11]);
    *(float4*)(my + 12) = make_float4(acc[12], acc[13], acc[14], acc[15]);
    my[16] = dsum;
  }
  asm volatile("s_waitcnt lgkmcnt(0)" ::: "memory");

  int c0 = lane * 2;
  int hh = lane >> 3, cc = (lane & 7) * 2;
  float o0 = 0.f, o1 = 0.f, den = 0.f;
  #pragma unroll
  for (int ee = 0; ee < 8; ++ee) {
    float2 tv = *(float2*)&red[w][ee][hh][cc];
    o0 += tv.x;
    o1 += tv.y;
    den += red[w][ee][hh][16];
  }
  float inv = 1.f / (den + 1e-16f);
  o0 *= inv;
  o1 *= inv;

  ushort2 xru = *(const ushort2*)(xr + (size_t)n * DIM + c0);
  float xr0 = bf2f(xru.x), xr1 = bf2f(xru.y);
  float wa0 = wbeta[c0] + wbeta[2 * DIM + c0];
  float wa1 = wbeta[c0 + 1] + wbeta[2 * DIM + c0 + 1];
  float wb0 = wbeta[DIM + c0] - wbeta[2 * DIM + c0];
  float wb1 = wbeta[DIM + c0 + 1] - wbeta[2 * DIM + c0 + 1];
  float bs = o0 * wa0 + o1 * wa1 + xr0 * wb0 + xr1 * wb1;
  #pragma unroll
  for (int off = 1; off < 64; off <<= 1) bs += __shfl_xor(bs, off);
  float beta = 1.f / (1.f + __expf(-bs));
  float y0 = fmaxf(beta * xr0 + (1.f - beta) * o0, 0.f);
  float y1 = fmaxf(beta * xr1 + (1.f - beta) * o1, 0.f);
  float rv0, rv1;
  if (RES_F32) {
    float2 rv = *(const float2*)((const float*)xres + (size_t)n * DIM + c0);
    rv0 = rv.x; rv1 = rv.y;
  } else {
    ushort2 ru = *(const ushort2*)((const ushort*)xres + (size_t)n * DIM + c0);
    rv0 = bf2f(ru.x); rv1 = bf2f(ru.y);
  }
  y0 += rv0;
  y1 += rv1;
  float s = y0 + y1;
  #pragma unroll
  for (int off = 1; off < 64; off <<= 1) s += __shfl_xor(s, off);
  float mu = s * (1.f / 128.f);
  float d0 = y0 - mu, d1 = y1 - mu;
  float vs = d0 * d0 + d1 * d1;
  #pragma unroll
  for (int off = 1; off < 64; off <<= 1) vs += __shfl_xor(vs, off);
  float rstd = rsqrtf(vs * (1.f / 128.f) + 1e-5f);
  float2 g = *(const float2*)(lng + c0);
  float2 b = *(const float2*)(lnb + c0);
  float out0 = d0 * rstd * g.x + b.x;
  float out1 = d1 * rstd * g.y + b.y;
  ushort2 ob;
  ob.x = f2bf(out0);
  ob.y = f2bf(out1);
  *(ushort2*)(xnextb + (size_t)n * DIM + c0) = ob;
}

// ---------------- launch ----------------

extern "C" void kernel_launch(void* const* d_in, const int* in_sizes, int n_in,
                              void* d_out, int out_size, void* d_ws, size_t ws_size,
                              hipStream_t stream) {
  const float* x_in = (const float*)d_in[0];
  const int* ei = (const int*)d_in[1];
  const float* Wq = (const float*)d_in[2];
  const float* bq = (const float*)d_in[3];
  const float* Wk = (const float*)d_in[4];
  const float* bk = (const float*)d_in[5];
  const float* Wv = (const float*)d_in[6];
  const float* bv = (const float*)d_in[7];
  const float* Wsk = (const float*)d_in[8];
  const float* bsk = (const float*)d_in[9];
  const float* Wb = (const float*)d_in[10];
  const float* lng = (const float*)d_in[11];
  const float* lnb = (const float*)d_in[12];
  const float* Wout = (const float*)d_in[13];
  const float* bout = (const float*)d_in[14];
  float* out = (float*)d_out;

  char* p = (char*)d_ws;
  auto alloc = [&](size_t bytes) {
    char* r = p;
    p += (bytes + 255) & ~(size_t)255;
    return r;
  };
  const size_t NB2 = (size_t)N_NODES * DIM * 2;
  ushort* xbb = (ushort*)alloc(NB2);  // bf16 x: GEMM input AND residual carrier
  ushort* qb = (ushort*)alloc(NB2);
  unsigned char* kvb = (unsigned char*)alloc((size_t)N_NODES * 256);
  ushort* xrb = (ushort*)alloc(NB2);
  ushort* wt = (ushort*)alloc((size_t)13 * DIM * DIM * 2);
  int* rowptr = (int*)alloc((N_NODES + 1) * 4);
  int* degc = (int*)alloc(N_NODES * 4);
  int* bsum = (int*)alloc(N_SCAN_BLKS * 4);
  int* csr_src = (int*)alloc(N_EDGES * 4);

  prep_kernel<<<PREP_TOTAL, 256, 0, stream>>>(Wq, Wk, Wv, Wsk, Wout, wt, degc, bsum);
  count_deg_kernel<<<(N_EDGES + 255) / 256, 256, 0, stream>>>(ei, degc);
  scan_lookback_kernel<<<N_SCAN_BLKS, SCAN_BLK, 0, stream>>>(degc, rowptr, bsum);
  scatter_kernel<<<(N_EDGES + 255) / 256, 256, 0, stream>>>(ei, rowptr, degc, csr_src);

  const int GX = (N_NODES + 127) / 128;  // 157
  for (int l = 0; l < NLAYER; ++l) {
    if (l == 0) {
      gemm_mfma_kernel<1><<<dim3(GX, 4), 256, 0, stream>>>(
          (const void*)x_in, wt + (size_t)l * 4 * DIM * DIM,
          bq + (size_t)l * DIM, bk + (size_t)l * DIM, bv + (size_t)l * DIM,
          bsk + (size_t)l * DIM,
          qb, kvb, kvb, xrb, 0, 2, 3, 0);
      attn_fused_kernel<1><<<N_NODES / 4, 256, 0, stream>>>(
          qb, kvb, xrb, (const void*)x_in, rowptr, csr_src,
          Wb + (size_t)l * 3 * DIM, lng + (size_t)l * DIM, lnb + (size_t)l * DIM,
          xbb);
    } else {
      gemm_mfma_kernel<0><<<dim3(GX, 4), 256, 0, stream>>>(
          (const void*)xbb, wt + (size_t)l * 4 * DIM * DIM,
          bq + (size_t)l * DIM, bk + (size_t)l * DIM, bv + (size_t)l * DIM,
          bsk + (size_t)l * DIM,
          qb, kvb, kvb, xrb, 0, 2, 3, 0);
      attn_fused_kernel<0><<<N_NODES / 4, 256, 0, stream>>>(
          qb, kvb, xrb, (const void*)xbb, rowptr, csr_src,
          Wb + (size_t)l * 3 * DIM, lng + (size_t)l * DIM, lnb + (size_t)l * DIM,
          xbb);
    }
  }
  gemm_mfma_kernel<0><<<dim3(GX, 1), 256, 0, stream>>>(
      (const void*)xbb, wt + (size_t)12 * DIM * DIM, bout, bout, bout, bout,
      out, out, out, out, 1, 1, 1, 1);
}